// Round 7
// baseline (268.047 us; speedup 1.0000x reference)
//
#include <hip/hip_runtime.h>
#include <hip/hip_bf16.h>

// WeightedLoss round 26: 256^2 tile, 16 waves x 64 thr (1024), spill-free.
// r25 A/B answered: pipelining r19's slices = NULL (105.7 vs 104; identical
// counters) -> slice-drain latency isn't the cost. Real structure: 2080
// blocks re-read the 6MB packed panels 67x (400MB of load_lds through the
// queued L2/L3 path) and each block serializes ~6 long-latency waits.
// r26 halves panel traffic (203MB) via 256^2 tiles WITHOUT the r20-r23
// spill trap: 16 waves of 64 keep acc[4][4]=64 regs/wave (VGPR ~112).
// 528 blocks, 128KB LDS dbuf, 1 blk/CU x 4 waves/SIMD. Waits recounted
// exactly (r25 had two no-op waits from a store miscount - fixed):
// per-thread VMEM L0:4 L1:4 |w4| O0:4 |w4| O1:4 F ST:8 |w12| O2:4 F SQ:8
// F |w20| O3:4 |w12| |w0|; diagonal non-store waves use {4,4,4,12,12,0}
// (vmcnt is per-wave; dostore is wave-uniform). Store layout bit-exact to
// r7 NT chunked layout via tile_encode + wid0=(wr&1)*2|(wc&1).
// Read: stats >=100us with clean counters -> traffic isn't the lever
// either; floor = serial slice dependency; pivot to loss_stream.
// ws: [0] Obp packed 4 MB | [4194304] Lnp packed 2 MB | [6291456] sq
//     [6324224] pos_sums | [6356992] neg_sums | [6389760] stats u32[3]
//     [6389824] simT fp16 2080x16384 (68.2 MB) | [74547264] eudT (68.2 MB)

#define B_N 8192
#define TILE 128
#define NTRI 2080
#define NSUP 528
#define WS_NEEDED 142704704ull

typedef __attribute__((ext_vector_type(8))) short bf16x8;
typedef __attribute__((ext_vector_type(4))) float f32x4;
typedef __attribute__((ext_vector_type(2))) _Float16 f16x2;
typedef __attribute__((ext_vector_type(4))) unsigned u32x4;

typedef const __attribute__((address_space(1))) void g_void;
typedef __attribute__((address_space(3))) void l_void;

__device__ __forceinline__ unsigned fenc(float f) {
    unsigned u = __float_as_uint(f);
    return (u & 0x80000000u) ? ~u : (u | 0x80000000u);
}
__device__ __forceinline__ float fdec(unsigned k) {
    unsigned u = (k & 0x80000000u) ? (k ^ 0x80000000u) : ~k;
    return __uint_as_float(u);
}
__device__ __forceinline__ unsigned pack2(float a, float b) {
    f16x2 p; p[0] = (_Float16)a; p[1] = (_Float16)b;
    return *(unsigned*)&p;
}

// Tile decode for the 64x64 128-tile triangle (loss kernels).
__device__ __forceinline__ void tile_decode(int b, int& bi, int& bj) {
    int si, sj, ti, tj;
    if (b < 544) {
        int sb = b / 136, w = b - sb * 136;
        int i = 0;
        while (w >= 16 - i) { w -= 16 - i; i++; }
        si = sb; sj = sb; ti = i; tj = i + w;
    } else {
        int q = (b - 544) >> 8, w = (b - 544) & 255;
        int i = 0;
        while (q >= 3 - i) { q -= 3 - i; i++; }
        si = i; sj = i + 1 + q;
        ti = w >> 4; tj = w & 15;
    }
    bi = si * 16 + ti; bj = sj * 16 + tj;
}

// Closed-form inverse of tile_decode (bi<=bj, 64x64 tile space).
__device__ __forceinline__ int tile_encode(int bi, int bj) {
    int si = bi >> 4, sj = bj >> 4, ti = bi & 15, tj = bj & 15;
    if (si == sj) return si * 136 + ti * 16 - (ti * (ti - 1)) / 2 + (tj - ti);
    int off = 3 * si - (si * (si - 1)) / 2 + (sj - si - 1);
    return 544 + off * 256 + ti * 16 + tj;
}

// ---------------------------------------------------------------- prep ----
__global__ __launch_bounds__(256) void prep_kernel(
    const float* __restrict__ outputs, const float* __restrict__ labels,
    __hip_bfloat16* __restrict__ Obp, __hip_bfloat16* __restrict__ Lnp,
    float* __restrict__ sq, float* __restrict__ pos_sums,
    float* __restrict__ neg_sums, unsigned* __restrict__ stats) {
    int g = blockIdx.x, tid = threadIdx.x;
    int rl = tid >> 4, c = tid & 15;
    int row = g * 16 + rl;
    __shared__ __align__(16) short tO[16][264];
    __shared__ __align__(16) short tL[16][136];

    float s = 0.f;
    #pragma unroll
    for (int k = 0; k < 4; k++) {
        f32x4 v = *(const f32x4*)&outputs[(size_t)row * 256 + c * 16 + k * 4];
        s += v[0]*v[0] + v[1]*v[1] + v[2]*v[2] + v[3]*v[3];
        __hip_bfloat16 b4[4];
        #pragma unroll
        for (int i = 0; i < 4; i++) b4[i] = __float2bfloat16(v[i]);
        *(uint2*)&tO[rl][c * 16 + k * 4] = *(uint2*)b4;
    }
    #pragma unroll
    for (int m = 1; m < 16; m <<= 1) s += __shfl_xor(s, m);
    if (c == 0) sq[row] = s;

    float ls = 0.f;
    f32x4 u0 = *(const f32x4*)&labels[(size_t)row * 128 + c * 8];
    f32x4 u1 = *(const f32x4*)&labels[(size_t)row * 128 + c * 8 + 4];
    ls += u0[0]*u0[0] + u0[1]*u0[1] + u0[2]*u0[2] + u0[3]*u0[3];
    ls += u1[0]*u1[0] + u1[1]*u1[1] + u1[2]*u1[2] + u1[3]*u1[3];
    #pragma unroll
    for (int m = 1; m < 16; m <<= 1) ls += __shfl_xor(ls, m);
    float inv = 1.f / (sqrtf(ls) + 1e-12f);
    {
        __hip_bfloat16 b4[4];
        #pragma unroll
        for (int i = 0; i < 4; i++) b4[i] = __float2bfloat16(u0[i] * inv);
        *(uint2*)&tL[rl][c * 8] = *(uint2*)b4;
        #pragma unroll
        for (int i = 0; i < 4; i++) b4[i] = __float2bfloat16(u1[i] * inv);
        *(uint2*)&tL[rl][c * 8 + 4] = *(uint2*)b4;
    }
    if (tid < 16) { pos_sums[g * 16 + tid] = 0.f; neg_sums[g * 16 + tid] = 0.f; }
    if (g == 0 && tid == 0) {
        stats[0] = 0xFFFFFFFFu; stats[1] = 0u; stats[2] = 0u;
    }
    __syncthreads();

    #pragma unroll
    for (int q = 0; q < 2; q++) {
        int sl = tid * 2 + q;
        int o = sl >> 4, rr = sl & 15;
        uint4 d = *(uint4*)&tO[rr][o * 8];
        *(uint4*)&Obp[(size_t)g * 4096 + (size_t)sl * 8] = d;
    }
    {
        int o = tid >> 4, rr = tid & 15;
        uint4 d = *(uint4*)&tL[rr][o * 8];
        *(uint4*)&Lnp[(size_t)g * 2048 + (size_t)tid * 8] = d;
    }
}

// ------------------------------------------------- staged slice gram ----
// (256-thread helpers kept for the loss_recompute fallback)
template<int KD8>
__device__ __forceinline__ void stage_slice(
    const short* __restrict__ P, int g0, int o0, short* L, int tid) {
    #pragma unroll
    for (int p = 0; p < 4; p++) {
        int u = p * 256 + tid;
        int gl = u >> 7, off = u & 127;
        size_t gu = ((size_t)(g0 + gl) * KD8 + o0) * 16 + off;
        __builtin_amdgcn_global_load_lds((g_void*)(P + gu * 8),
                                         (l_void*)(L + (size_t)u * 8), 16, 0, 0);
    }
}

__device__ __forceinline__ void mfma_slice(
    const short* As, const short* Bs, int wm4, int wn4,
    int l15, int quad, f32x4 (&acc)[4][4]) {
    #pragma unroll
    for (int kc = 0; kc < 2; kc++) {
        bf16x8 a[4], b[4];
        #pragma unroll
        for (int mi = 0; mi < 4; mi++)
            a[mi] = *(const bf16x8*)&As[((wm4 + mi) * 128
                                         + (kc * 4 + quad) * 16 + l15) * 8];
        #pragma unroll
        for (int ni = 0; ni < 4; ni++)
            b[ni] = *(const bf16x8*)&Bs[((wn4 + ni) * 128
                                         + (kc * 4 + quad) * 16 + l15) * 8];
        #pragma unroll
        for (int mi = 0; mi < 4; mi++)
            #pragma unroll
            for (int ni = 0; ni < 4; ni++)
                acc[mi][ni] = __builtin_amdgcn_mfma_f32_16x16x32_bf16(
                    a[mi], b[ni], acc[mi][ni], 0, 0, 0);
    }
}

__device__ __forceinline__ void zero_acc(f32x4 (&acc)[4][4]) {
    #pragma unroll
    for (int mi = 0; mi < 4; mi++)
        #pragma unroll
        for (int ni = 0; ni < 4; ni++) {
            f32x4 z = {0.f, 0.f, 0.f, 0.f};
            acc[mi][ni] = z;
        }
}

// (serial-staged gram kept for the loss_recompute fallback)
template<int KD8, int NS>
__device__ __forceinline__ void gram_staged(
    const short* __restrict__ P, int gA0, int gB0,
    short* As, short* Bs, int tid, int wm4, int wn4,
    int l15, int quad, f32x4 (&acc)[4][4]) {
    #pragma unroll
    for (int s = 0; s < NS; s++) {
        __syncthreads();
        stage_slice<KD8>(P, gA0, s * 8, As, tid);
        stage_slice<KD8>(P, gB0, s * 8, Bs, tid);
        __syncthreads();
        mfma_slice(As, Bs, wm4, wn4, l15, quad, acc);
    }
}

// 1024-thread staging: one 256-row x 64-K panel slice (2048 16B units).
__device__ __forceinline__ void stage1024(const short* __restrict__ P, int g0,
                                          int kd8, int o0, short* L, int tid) {
    #pragma unroll
    for (int p = 0; p < 2; p++) {
        int u = p * 1024 + tid;
        int gl = u >> 7, off = u & 127;
        size_t gu = ((size_t)(g0 + gl) * kd8 + o0) * 16 + off;
        __builtin_amdgcn_global_load_lds((g_void*)(P + gu * 8),
                                         (l_void*)(L + (size_t)u * 8), 16, 0, 0);
    }
}

#define VMCNT(n) asm volatile("s_waitcnt vmcnt(" #n ")" ::: "memory")
#define BAR() __builtin_amdgcn_s_barrier()
#define FENCE() asm volatile("" ::: "memory")

// ---------------------------------------------------------------- stats ----
// 256^2 tile per block, 16 waves (4x4 grid of 64x64 wave-tiles), 1024 thr.
// acc[4][4] = 64 regs/wave (spill-free). 128KB double-buffered LDS, counted
// vmcnt pipeline with EXACT per-thread counts (per-wave vmcnt: diagonal
// non-store waves get their own wave-uniform wait constants).
__global__ __launch_bounds__(1024, 4) void stats_kernel(
    const short* __restrict__ Lnp, const short* __restrict__ Obp,
    const float* __restrict__ sq, unsigned* __restrict__ stats,
    unsigned* __restrict__ simT, unsigned* __restrict__ eudT, int store) {
    // triangular supertile decode (32x32, 528 cells)
    int bt = blockIdx.x, BI = 0;
    while (bt >= 32 - BI) { bt -= 32 - BI; BI++; }
    int BJ = BI + bt;

    int tid = threadIdx.x, lane = tid & 63, wid = tid >> 6;
    int wr = wid >> 2, wc = wid & 3;          // 4x4 wave grid
    int tr = wr >> 1, tc = wc >> 1;           // 128-subtile coords
    int l15 = lane & 15, quad = lane >> 4;
    int wm4 = wr * 4, wn4 = wc * 4;           // 16-row-group indices

    __shared__ __align__(16) short As[2][16384];
    __shared__ __align__(16) short Bs[2][16384];
    __shared__ float red[3][16];

    int gA = BI * 16, gB = BJ * 16;
    bool dostore = store && !(BI == BJ && tr == 1 && tc == 0);
    int b128 = tile_encode(BI * 2 + tr, BJ * 2 + tc);
    int wid0 = ((wr & 1) << 1) | (wc & 1);    // wave id within 128-tile
    int tid128 = wid0 * 64 + lane;
    size_t blkbase = (size_t)b128 * 8192 + (size_t)tid128 * 4;

    float lmin = 1e30f, lmax = -1e30f, dmax = 0.f;
    f32x4 acc[4][4];

    // ---- labels gram: L0, L1 (K=128 -> 2 slices of 64) ----
    zero_acc(acc);
    stage1024(Lnp, gA, 16, 0, &As[0][0], tid);   // L0  [4]
    stage1024(Lnp, gB, 16, 0, &Bs[0][0], tid);
    stage1024(Lnp, gA, 16, 8, &As[1][0], tid);   // L1  [8]
    stage1024(Lnp, gB, 16, 8, &Bs[1][0], tid);
    VMCNT(4); BAR();                              // L0 ready
    mfma_slice(&As[0][0], &Bs[0][0], wm4, wn4, l15, quad, acc);
    BAR();                                        // buf0 readers done
    stage1024(Obp, gA, 32, 0, &As[0][0], tid);   // O0  [L1:4 + O0:4]
    stage1024(Obp, gB, 32, 0, &Bs[0][0], tid);
    VMCNT(4); BAR();                              // L1 ready
    mfma_slice(&As[1][0], &Bs[1][0], wm4, wn4, l15, quad, acc);
    BAR();                                        // buf1 readers done
    stage1024(Obp, gA, 32, 8, &As[1][0], tid);   // O1  [O0:4 + O1:4]
    stage1024(Obp, gB, 32, 8, &Bs[1][0], tid);
    FENCE();                                      // pin: O1 before ST

    // ---- sim epilogue: pack + min/max + NT stores ----
    #pragma unroll
    for (int mi = 0; mi < 4; mi++) {
        u32x4 v0, v1;
        #pragma unroll
        for (int ni = 0; ni < 4; ni++)
            #pragma unroll
            for (int h = 0; h < 2; h++) {
                float s0 = acc[mi][ni][2 * h], s1 = acc[mi][ni][2 * h + 1];
                lmin = fminf(lmin, fminf(s0, s1));
                lmax = fmaxf(lmax, fmaxf(s0, s1));
                int j = ni * 2 + h;
                unsigned pk = pack2(s0, s1);
                if (j < 4) v0[j] = pk; else v1[j - 4] = pk;
            }
        if (dostore) {
            __builtin_nontemporal_store(v0, (u32x4*)(simT + blkbase + (mi * 2 + 0) * 1024));
            __builtin_nontemporal_store(v1, (u32x4*)(simT + blkbase + (mi * 2 + 1) * 1024));
        }
    }                      // store waves: [O0:4 + O1:4 + ST:8] | else [8]
    FENCE();

    // ---- outputs gram: O0..O3 pipelined ----
    zero_acc(acc);
    if (dostore) { VMCNT(12); } else { VMCNT(4); }   // retire O0 (oldest 4)
    BAR();
    mfma_slice(&As[0][0], &Bs[0][0], wm4, wn4, l15, quad, acc);
    BAR();                                        // buf0 free
    stage1024(Obp, gA, 32, 16, &As[0][0], tid);  // O2
    stage1024(Obp, gB, 32, 16, &Bs[0][0], tid);
    FENCE();                                      // pin: O2 before SQ
    // sq prefetch: 4x f32x4 + 4 scalar = 8 VMEM
    float sqj[4]; f32x4 sqi4[4];
    {
        int rqa = BI * 256 + wr * 64 + quad * 4;
        int cqa = BJ * 256 + wc * 64 + l15;
        #pragma unroll
        for (int mi = 0; mi < 4; mi++)
            sqi4[mi] = *(const f32x4*)&sq[rqa + mi * 16];
        #pragma unroll
        for (int ni = 0; ni < 4; ni++)
            sqj[ni] = sq[cqa + ni * 16];
    }
    FENCE();                                      // pin: SQ before wait
    // store waves: [O1:4 + ST:8 + O2:4 + SQ:8]=24, retire O1 -> w20
    // else:        [O1:4 + O2:4 + SQ:8]=16,       retire O1 -> w12
    if (dostore) { VMCNT(20); } else { VMCNT(12); }
    BAR();
    mfma_slice(&As[1][0], &Bs[1][0], wm4, wn4, l15, quad, acc);
    BAR();                                        // buf1 free
    stage1024(Obp, gA, 32, 24, &As[1][0], tid);  // O3
    stage1024(Obp, gB, 32, 24, &Bs[1][0], tid);
    // store: [ST:8 + O2:4 + SQ:8 + O3:4]=24, retire ST+O2 (12) -> w12
    // else:  [O2:4 + SQ:8 + O3:4]=16,        retire O2 (4)     -> w12
    VMCNT(12); BAR();                             // O2 ready
    mfma_slice(&As[0][0], &Bs[0][0], wm4, wn4, l15, quad, acc);
    VMCNT(0); BAR();                              // O3 ready (SQ retired too)
    mfma_slice(&As[1][0], &Bs[1][0], wm4, wn4, l15, quad, acc);

    // ---- eud epilogue ----
    #pragma unroll
    for (int mi = 0; mi < 4; mi++) {
        f32x4 sqi = sqi4[mi];
        u32x4 v0, v1;
        #pragma unroll
        for (int ni = 0; ni < 4; ni++)
            #pragma unroll
            for (int h = 0; h < 2; h++) {
                float d20 = fmaxf(sqi[2*h]   + sqj[ni] - 2.f * acc[mi][ni][2*h],   0.f);
                float d21 = fmaxf(sqi[2*h+1] + sqj[ni] - 2.f * acc[mi][ni][2*h+1], 0.f);
                dmax = fmaxf(dmax, fmaxf(d20, d21));
                float e0 = (d20 > 0.f) ? sqrtf(d20) : 0.f;
                float e1 = (d21 > 0.f) ? sqrtf(d21) : 0.f;
                int j = ni * 2 + h;
                unsigned pk = pack2(e0, e1);
                if (j < 4) v0[j] = pk; else v1[j - 4] = pk;
            }
        if (dostore) {
            __builtin_nontemporal_store(v0, (u32x4*)(eudT + blkbase + (mi * 2 + 0) * 1024));
            __builtin_nontemporal_store(v1, (u32x4*)(eudT + blkbase + (mi * 2 + 1) * 1024));
        }
    }

    // ---- reductions ----
    #pragma unroll
    for (int m = 1; m < 64; m <<= 1) {
        lmin = fminf(lmin, __shfl_xor(lmin, m));
        lmax = fmaxf(lmax, __shfl_xor(lmax, m));
        dmax = fmaxf(dmax, __shfl_xor(dmax, m));
    }
    if (lane == 0) { red[0][wid] = lmin; red[1][wid] = lmax; red[2][wid] = dmax; }
    __syncthreads();
    if (tid == 0) {
        lmin = red[0][0]; lmax = red[1][0]; dmax = red[2][0];
        #pragma unroll
        for (int w = 1; w < 16; w++) {
            lmin = fminf(lmin, red[0][w]);
            lmax = fmaxf(lmax, red[1][w]);
            dmax = fmaxf(dmax, red[2][w]);
        }
        atomicMin(&stats[0], fenc(lmin));
        atomicMax(&stats[1], fenc(lmax));
        atomicMax(&stats[2], fenc(dmax));
    }
}

// ----------------------------------------------------------- loss stream ----
// Pure streaming epilogue (r7-verified): coalesced NT dwordx4 reads,
// exp terms, row+col sums, one atomic per row per block.
__global__ __launch_bounds__(256) void loss_stream_kernel(
    const unsigned* __restrict__ simT, const unsigned* __restrict__ eudT,
    const unsigned* __restrict__ stats,
    float* __restrict__ pos_sums, float* __restrict__ neg_sums) {
    int bi, bj;
    tile_decode(blockIdx.x, bi, bj);
    int tid = threadIdx.x, lane = tid & 63, wid = tid >> 6;
    int wm = (wid >> 1) * 64, wn = (wid & 1) * 64;
    int l15 = lane & 15, quad = lane >> 4;
    size_t tB = (size_t)blockIdx.x * 8192 + (size_t)tid * 4;

    float smin = fdec(stats[0]);
    float smax = fdec(stats[1]);
    float d2max = fdec(stats[2]);
    float invr = 1.f / (smax - smin);
    float invem = rsqrtf(d2max);

    __shared__ float rP[TILE][2], rN[TILE][2];
    __shared__ float cP[TILE][2], cN[TILE][2];
    float cpsum[4] = {0.f, 0.f, 0.f, 0.f};
    float cnsum[4] = {0.f, 0.f, 0.f, 0.f};

    #pragma unroll
    for (int mi = 0; mi < 4; mi++) {
        u32x4 s0 = __builtin_nontemporal_load((const u32x4*)(simT + tB + (mi * 2 + 0) * 1024));
        u32x4 s1 = __builtin_nontemporal_load((const u32x4*)(simT + tB + (mi * 2 + 1) * 1024));
        u32x4 e0 = __builtin_nontemporal_load((const u32x4*)(eudT + tB + (mi * 2 + 0) * 1024));
        u32x4 e1 = __builtin_nontemporal_load((const u32x4*)(eudT + tB + (mi * 2 + 1) * 1024));
        float ps[4] = {0.f, 0.f, 0.f, 0.f};
        float ns[4] = {0.f, 0.f, 0.f, 0.f};
        #pragma unroll
        for (int j = 0; j < 8; j++) {
            unsigned sv = (j < 4) ? s0[j] : s1[j - 4];
            unsigned ev = (j < 4) ? e0[j] : e1[j - 4];
            int ni = j >> 1, h = j & 1;
            f16x2 spair = *(f16x2*)&sv;
            f16x2 epair = *(f16x2*)&ev;
            #pragma unroll
            for (int e = 0; e < 2; e++) {
                float sn = ((float)spair[e] - smin) * invr;
                float dist = (float)epair[e] * invem + sn;
                bool pos = sn > 0.5f;   // TAU
                float pv = pos ? __expf(dist) : 0.f;
                float nv = pos ? 0.f : __expf(1.0f - dist);  // MAG = 1
                ps[2 * h + e] += pv;  ns[2 * h + e] += nv;
                cpsum[ni] += pv;  cnsum[ni] += nv;
            }
        }
        #pragma unroll
        for (int r = 0; r < 4; r++) {
            #pragma unroll
            for (int m = 1; m < 16; m <<= 1) {
                ps[r] += __shfl_xor(ps[r], m);
                ns[r] += __shfl_xor(ns[r], m);
            }
            if (l15 == 0) {
                int rr = wm + mi * 16 + quad * 4 + r;
                rP[rr][wid & 1] = ps[r];
                rN[rr][wid & 1] = ns[r];
            }
        }
    }
    #pragma unroll
    for (int ni = 0; ni < 4; ni++) {
        #pragma unroll
        for (int m = 16; m < 64; m <<= 1) {
            cpsum[ni] += __shfl_xor(cpsum[ni], m);
            cnsum[ni] += __shfl_xor(cnsum[ni], m);
        }
        if (quad == 0) {
            int cc = wn + ni * 16 + l15;
            cP[cc][wid >> 1] = cpsum[ni];
            cN[cc][wid >> 1] = cnsum[ni];
        }
    }
    __syncthreads();
    if (tid < TILE) {
        atomicAdd(&pos_sums[bi * TILE + tid], rP[tid][0] + rP[tid][1]);
        atomicAdd(&neg_sums[bi * TILE + tid], rN[tid][0] + rN[tid][1]);
        if (bi != bj) {
            atomicAdd(&pos_sums[bj * TILE + tid], cP[tid][0] + cP[tid][1]);
            atomicAdd(&neg_sums[bj * TILE + tid], cN[tid][0] + cN[tid][1]);
        }
    }
}

// ------------------------------------------ loss fallback (recompute, r18) ----
__global__ __launch_bounds__(256, 2) void loss_recompute_kernel(
    const short* __restrict__ Lnp, const short* __restrict__ Obp,
    const float* __restrict__ sq, const unsigned* __restrict__ stats,
    float* __restrict__ pos_sums, float* __restrict__ neg_sums) {
    int bi, bj;
    tile_decode(blockIdx.x, bi, bj);
    int tid = threadIdx.x, lane = tid & 63, wid = tid >> 6;
    int wm = (wid >> 1) * 64, wn = (wid & 1) * 64;
    int wm4 = (wid >> 1) * 4, wn4 = (wid & 1) * 4;
    int l15 = lane & 15, quad = lane >> 4;
    int rB = bi * TILE, cB = bj * TILE;

    __shared__ __align__(16) short As[1024 * 8];
    __shared__ __align__(16) short Bs[1024 * 8];
    __shared__ unsigned simW[256 * 33];
    __shared__ float rP[TILE][2], rN[TILE][2];
    __shared__ float cP[TILE][2], cN[TILE][2];
    unsigned* my = &simW[tid * 33];

    f32x4 acc[4][4];

    zero_acc(acc);
    gram_staged<16, 2>(Lnp, bi * 8, bj * 8, As, Bs, tid, wm4, wn4, l15, quad, acc);
    #pragma unroll
    for (int mi = 0; mi < 4; mi++)
        #pragma unroll
        for (int ni = 0; ni < 4; ni++) {
            my[(mi * 4 + ni) * 2 + 0] = pack2(acc[mi][ni][0], acc[mi][ni][1]);
            my[(mi * 4 + ni) * 2 + 1] = pack2(acc[mi][ni][2], acc[mi][ni][3]);
        }

    zero_acc(acc);
    gram_staged<32, 4>(Obp, bi * 8, bj * 8, As, Bs, tid, wm4, wn4, l15, quad, acc);

    float smin = fdec(stats[0]);
    float smax = fdec(stats[1]);
    float d2max = fdec(stats[2]);
    float invr = 1.f / (smax - smin);
    float invem = rsqrtf(d2max);

    float sqj[4];
    #pragma unroll
    for (int ni = 0; ni < 4; ni++) sqj[ni] = sq[cB + wn + ni * 16 + l15];
    float cpsum[4] = {0.f, 0.f, 0.f, 0.f};
    float cnsum[4] = {0.f, 0.f, 0.f, 0.f};

    #pragma unroll
    for (int mi = 0; mi < 4; mi++) {
        f32x4 sqi = *(const f32x4*)&sq[rB + wm + mi * 16 + quad * 4];
        float ps[4] = {0.f, 0.f, 0.f, 0.f};
        float ns[4] = {0.f, 0.f, 0.f, 0.f};
        #pragma unroll
        for (int ni = 0; ni < 4; ni++) {
            f16x2 s01 = ((const f16x2*)my)[(mi * 4 + ni) * 2 + 0];
            f16x2 s23 = ((const f16x2*)my)[(mi * 4 + ni) * 2 + 1];
            #pragma unroll
            for (int r = 0; r < 4; r++) {
                float sraw = (r < 2) ? (float)s01[r] : (float)s23[r - 2];
                float sn = (sraw - smin) * invr;
                float g = acc[mi][ni][r];
                float d2 = fmaxf(sqi[r] + sqj[ni] - 2.f * g, 0.f);
                float eud = (d2 > 0.f) ? sqrtf(d2) * invem : 0.f;
                float dist = eud + sn;
                bool pos = sn > 0.5f;
                float pv = pos ? __expf(dist) : 0.f;
                float nv = pos ? 0.f : __expf(1.0f - dist);
                ps[r] += pv;  ns[r] += nv;
                cpsum[ni] += pv;  cnsum[ni] += nv;
            }
        }
        #pragma unroll
        for (int r = 0; r < 4; r++) {
            #pragma unroll
            for (int m = 1; m < 16; m <<= 1) {
                ps[r] += __shfl_xor(ps[r], m);
                ns[r] += __shfl_xor(ns[r], m);
            }
            if (l15 == 0) {
                int rr = wm + mi * 16 + quad * 4 + r;
                rP[rr][wid & 1] = ps[r];
                rN[rr][wid & 1] = ns[r];
            }
        }
    }
    #pragma unroll
    for (int ni = 0; ni < 4; ni++) {
        #pragma unroll
        for (int m = 16; m < 64; m <<= 1) {
            cpsum[ni] += __shfl_xor(cpsum[ni], m);
            cnsum[ni] += __shfl_xor(cnsum[ni], m);
        }
        if (quad == 0) {
            int cc = wn + ni * 16 + l15;
            cP[cc][wid >> 1] = cpsum[ni];
            cN[cc][wid >> 1] = cnsum[ni];
        }
    }
    __syncthreads();
    if (tid < TILE) {
        atomicAdd(&pos_sums[bi * TILE + tid], rP[tid][0] + rP[tid][1]);
        atomicAdd(&neg_sums[bi * TILE + tid], rN[tid][0] + rN[tid][1]);
        if (bi != bj) {
            atomicAdd(&pos_sums[bj * TILE + tid], cP[tid][0] + cP[tid][1]);
            atomicAdd(&neg_sums[bj * TILE + tid], cN[tid][0] + cN[tid][1]);
        }
    }
}

// ------------------------------------------------------------- finalize ----
__global__ __launch_bounds__(256) void finalize_kernel(
    const float* __restrict__ pos_sums, const float* __restrict__ neg_sums,
    float* __restrict__ out) {
    int t = threadIdx.x;
    float acc = 0.f;
    for (int i = t; i < B_N; i += 256) {
        float p = pos_sums[i], n = neg_sums[i];
        float pl = fmaxf(logf(p), 0.f);
        float nl = (n > 0.f) ? fmaxf(logf(n), 0.f) : 0.f;
        acc += pl + nl;
    }
    #pragma unroll
    for (int m = 1; m < 64; m <<= 1) acc += __shfl_xor(acc, m);
    __shared__ float w4[4];
    if ((t & 63) == 0) w4[t >> 6] = acc;
    __syncthreads();
    if (t == 0) out[0] = (w4[0] + w4[1] + w4[2] + w4[3]) / (float)B_N;
}

// ------------------------------------------------------------------ entry ----
extern "C" void kernel_launch(void* const* d_in, const int* in_sizes, int n_in,
                              void* d_out, int out_size, void* d_ws, size_t ws_size,
                              hipStream_t stream) {
    const float* outputs = (const float*)d_in[0];
    const float* labels  = (const float*)d_in[1];
    float* out = (float*)d_out;
    char* ws = (char*)d_ws;
    __hip_bfloat16* Obp = (__hip_bfloat16*)(ws);
    __hip_bfloat16* Lnp = (__hip_bfloat16*)(ws + 4194304);
    float* sq           = (float*)(ws + 6291456);
    float* pos_sums     = (float*)(ws + 6324224);
    float* neg_sums     = (float*)(ws + 6356992);
    unsigned* stats     = (unsigned*)(ws + 6389760);
    unsigned* simT      = (unsigned*)(ws + 6389824);
    unsigned* eudT      = (unsigned*)(ws + 74547264);
    int big = (ws_size >= WS_NEEDED) ? 1 : 0;

    prep_kernel<<<B_N / 16, 256, 0, stream>>>(outputs, labels, Obp, Lnp, sq,
                                              pos_sums, neg_sums, stats);
    stats_kernel<<<NSUP, 1024, 0, stream>>>((const short*)Lnp, (const short*)Obp,
                                            sq, stats, simT, eudT, big);
    if (big)
        loss_stream_kernel<<<NTRI, 256, 0, stream>>>(simT, eudT, stats,
                                                     pos_sums, neg_sums);
    else
        loss_recompute_kernel<<<NTRI, 256, 0, stream>>>((const short*)Lnp,
                                                        (const short*)Obp,
                                                        sq, stats,
                                                        pos_sums, neg_sums);
    finalize_kernel<<<1, 256, 0, stream>>>(pos_sums, neg_sums, out);
}

// Round 8
// 209.120 us; speedup vs baseline: 1.2818x; 1.2818x over previous
//
#include <hip/hip_runtime.h>
#include <hip/hip_bf16.h>

// WeightedLoss round 27: deepen prefetch distance, not wave count.
// r20-r26 law: MFMA gram needs ~110 arch + 64 acc ~= 176 regs/wave; any
// geometry requiring >2 waves/EU residency spills (r26: VGPR 64 + scratch
// signature on FETCH/WRITE). TLP is hard-capped at 8 waves/CU. r25 showed
// depth-1 pipelining is null (compute/slice ~300cy << L ~5kcy). r27 keeps
// r19/r25's exact geometry (2080 blk x 256 thr, acc[4][4], 64KB LDS,
// 2 blk/CU) but stages 12x 32-K slices with 4 buffers resident: steady
// state waits for data issued 4 slices ago -> exposed ~= max(C, L/4).
// vmcnt constants derived from an explicit queue model; store/no-store
// paths have different in-queue NT-store counts -> kernel templated on
// STORE (shared constants would race the no-store path). VMCNT asm
// memory clobbers pin all cross-type VMEM ordering.
// Read: stats ~105 unchanged + clean counters => stats at structural
// floor; pivot to loss/prep side.
// ws: [0] Obp packed 4 MB | [4194304] Lnp packed 2 MB | [6291456] sq
//     [6324224] pos_sums | [6356992] neg_sums | [6389760] stats u32[3]
//     [6389824] simT fp16 2080x16384 (68.2 MB) | [74547264] eudT (68.2 MB)

#define B_N 8192
#define TILE 128
#define NTRI 2080
#define WS_NEEDED 142704704ull

typedef __attribute__((ext_vector_type(8))) short bf16x8;
typedef __attribute__((ext_vector_type(4))) float f32x4;
typedef __attribute__((ext_vector_type(2))) _Float16 f16x2;
typedef __attribute__((ext_vector_type(4))) unsigned u32x4;

typedef const __attribute__((address_space(1))) void g_void;
typedef __attribute__((address_space(3))) void l_void;

__device__ __forceinline__ unsigned fenc(float f) {
    unsigned u = __float_as_uint(f);
    return (u & 0x80000000u) ? ~u : (u | 0x80000000u);
}
__device__ __forceinline__ float fdec(unsigned k) {
    unsigned u = (k & 0x80000000u) ? (k ^ 0x80000000u) : ~k;
    return __uint_as_float(u);
}
__device__ __forceinline__ unsigned pack2(float a, float b) {
    f16x2 p; p[0] = (_Float16)a; p[1] = (_Float16)b;
    return *(unsigned*)&p;
}

// Tile decode for the 64x64 128-tile triangle. bi<=bj always.
__device__ __forceinline__ void tile_decode(int b, int& bi, int& bj) {
    int si, sj, ti, tj;
    if (b < 544) {
        int sb = b / 136, w = b - sb * 136;
        int i = 0;
        while (w >= 16 - i) { w -= 16 - i; i++; }
        si = sb; sj = sb; ti = i; tj = i + w;
    } else {
        int q = (b - 544) >> 8, w = (b - 544) & 255;
        int i = 0;
        while (q >= 3 - i) { q -= 3 - i; i++; }
        si = i; sj = i + 1 + q;
        ti = w >> 4; tj = w & 15;
    }
    bi = si * 16 + ti; bj = sj * 16 + tj;
}

// ---------------------------------------------------------------- prep ----
__global__ __launch_bounds__(256) void prep_kernel(
    const float* __restrict__ outputs, const float* __restrict__ labels,
    __hip_bfloat16* __restrict__ Obp, __hip_bfloat16* __restrict__ Lnp,
    float* __restrict__ sq, float* __restrict__ pos_sums,
    float* __restrict__ neg_sums, unsigned* __restrict__ stats) {
    int g = blockIdx.x, tid = threadIdx.x;
    int rl = tid >> 4, c = tid & 15;
    int row = g * 16 + rl;
    __shared__ __align__(16) short tO[16][264];
    __shared__ __align__(16) short tL[16][136];

    float s = 0.f;
    #pragma unroll
    for (int k = 0; k < 4; k++) {
        f32x4 v = *(const f32x4*)&outputs[(size_t)row * 256 + c * 16 + k * 4];
        s += v[0]*v[0] + v[1]*v[1] + v[2]*v[2] + v[3]*v[3];
        __hip_bfloat16 b4[4];
        #pragma unroll
        for (int i = 0; i < 4; i++) b4[i] = __float2bfloat16(v[i]);
        *(uint2*)&tO[rl][c * 16 + k * 4] = *(uint2*)b4;
    }
    #pragma unroll
    for (int m = 1; m < 16; m <<= 1) s += __shfl_xor(s, m);
    if (c == 0) sq[row] = s;

    float ls = 0.f;
    f32x4 u0 = *(const f32x4*)&labels[(size_t)row * 128 + c * 8];
    f32x4 u1 = *(const f32x4*)&labels[(size_t)row * 128 + c * 8 + 4];
    ls += u0[0]*u0[0] + u0[1]*u0[1] + u0[2]*u0[2] + u0[3]*u0[3];
    ls += u1[0]*u1[0] + u1[1]*u1[1] + u1[2]*u1[2] + u1[3]*u1[3];
    #pragma unroll
    for (int m = 1; m < 16; m <<= 1) ls += __shfl_xor(ls, m);
    float inv = 1.f / (sqrtf(ls) + 1e-12f);
    {
        __hip_bfloat16 b4[4];
        #pragma unroll
        for (int i = 0; i < 4; i++) b4[i] = __float2bfloat16(u0[i] * inv);
        *(uint2*)&tL[rl][c * 8] = *(uint2*)b4;
        #pragma unroll
        for (int i = 0; i < 4; i++) b4[i] = __float2bfloat16(u1[i] * inv);
        *(uint2*)&tL[rl][c * 8 + 4] = *(uint2*)b4;
    }
    if (tid < 16) { pos_sums[g * 16 + tid] = 0.f; neg_sums[g * 16 + tid] = 0.f; }
    if (g == 0 && tid == 0) {
        stats[0] = 0xFFFFFFFFu; stats[1] = 0u; stats[2] = 0u;
    }
    __syncthreads();

    #pragma unroll
    for (int q = 0; q < 2; q++) {
        int sl = tid * 2 + q;
        int o = sl >> 4, rr = sl & 15;
        uint4 d = *(uint4*)&tO[rr][o * 8];
        *(uint4*)&Obp[(size_t)g * 4096 + (size_t)sl * 8] = d;
    }
    {
        int o = tid >> 4, rr = tid & 15;
        uint4 d = *(uint4*)&tL[rr][o * 8];
        *(uint4*)&Lnp[(size_t)g * 2048 + (size_t)tid * 8] = d;
    }
}

// ------------------------------------------------- staged slice gram ----
// (64-K helpers kept for the loss_recompute fallback)
template<int KD8>
__device__ __forceinline__ void stage_slice(
    const short* __restrict__ P, int g0, int o0, short* L, int tid) {
    #pragma unroll
    for (int p = 0; p < 4; p++) {
        int u = p * 256 + tid;
        int gl = u >> 7, off = u & 127;
        size_t gu = ((size_t)(g0 + gl) * KD8 + o0) * 16 + off;
        __builtin_amdgcn_global_load_lds((g_void*)(P + gu * 8),
                                         (l_void*)(L + (size_t)u * 8), 16, 0, 0);
    }
}

__device__ __forceinline__ void mfma_slice(
    const short* As, const short* Bs, int wm4, int wn4,
    int l15, int quad, f32x4 (&acc)[4][4]) {
    #pragma unroll
    for (int kc = 0; kc < 2; kc++) {
        bf16x8 a[4], b[4];
        #pragma unroll
        for (int mi = 0; mi < 4; mi++)
            a[mi] = *(const bf16x8*)&As[((wm4 + mi) * 128
                                         + (kc * 4 + quad) * 16 + l15) * 8];
        #pragma unroll
        for (int ni = 0; ni < 4; ni++)
            b[ni] = *(const bf16x8*)&Bs[((wn4 + ni) * 128
                                         + (kc * 4 + quad) * 16 + l15) * 8];
        #pragma unroll
        for (int mi = 0; mi < 4; mi++)
            #pragma unroll
            for (int ni = 0; ni < 4; ni++)
                acc[mi][ni] = __builtin_amdgcn_mfma_f32_16x16x32_bf16(
                    a[mi], b[ni], acc[mi][ni], 0, 0, 0);
    }
}

__device__ __forceinline__ void zero_acc(f32x4 (&acc)[4][4]) {
    #pragma unroll
    for (int mi = 0; mi < 4; mi++)
        #pragma unroll
        for (int ni = 0; ni < 4; ni++) {
            f32x4 z = {0.f, 0.f, 0.f, 0.f};
            acc[mi][ni] = z;
        }
}

template<int KD8, int NS>
__device__ __forceinline__ void gram_staged(
    const short* __restrict__ P, int gA0, int gB0,
    short* As, short* Bs, int tid, int wm4, int wn4,
    int l15, int quad, f32x4 (&acc)[4][4]) {
    #pragma unroll
    for (int s = 0; s < NS; s++) {
        __syncthreads();
        stage_slice<KD8>(P, gA0, s * 8, As, tid);
        stage_slice<KD8>(P, gB0, s * 8, Bs, tid);
        __syncthreads();
        mfma_slice(As, Bs, wm4, wn4, l15, quad, acc);
    }
}

// ---- 32-K slice machinery (r27 stats pipeline) ----
// Slice buffer layout [8 groups][4 k8][16 rows] = 512 units (8KB).
// Packed panels are K-outer within 16-row groups: global unit
// = (group)*KD8*16 + k8*16 + row.
template<int KD8>
__device__ __forceinline__ void stage32(const short* __restrict__ P, int g0,
                                        int ko8, short* L, int tid) {
    #pragma unroll
    for (int p = 0; p < 2; p++) {
        int u = p * 256 + tid;
        int gl = u >> 6, k8l = (u >> 4) & 3, r = u & 15;
        size_t gu = ((size_t)(g0 + gl) * KD8 + ko8 + k8l) * 16 + r;
        __builtin_amdgcn_global_load_lds((g_void*)(P + gu * 8),
                                         (l_void*)(L + (size_t)u * 8), 16, 0, 0);
    }
}

__device__ __forceinline__ void mfma_slice32(
    const short* As, const short* Bs, int wm4, int wn4,
    int l15, int quad, f32x4 (&acc)[4][4]) {
    bf16x8 a[4], b[4];
    #pragma unroll
    for (int mi = 0; mi < 4; mi++)
        a[mi] = *(const bf16x8*)&As[((wm4 + mi) * 64 + quad * 16 + l15) * 8];
    #pragma unroll
    for (int ni = 0; ni < 4; ni++)
        b[ni] = *(const bf16x8*)&Bs[((wn4 + ni) * 64 + quad * 16 + l15) * 8];
    #pragma unroll
    for (int mi = 0; mi < 4; mi++)
        #pragma unroll
        for (int ni = 0; ni < 4; ni++)
            acc[mi][ni] = __builtin_amdgcn_mfma_f32_16x16x32_bf16(
                a[mi], b[ni], acc[mi][ni], 0, 0, 0);
}

#define VMCNT(n) asm volatile("s_waitcnt vmcnt(" #n ")" ::: "memory")
#define BAR() __builtin_amdgcn_s_barrier()
#define FENCE() asm volatile("" ::: "memory")

// ---------------------------------------------------------------- stats ----
// r19 geometry + 12x 32-K slices, 4 buffers resident (depth-4 prefetch).
// Queue model (per-thread VMEM, 4 loads per slice-pair, STORE=1 path):
//  init L0..L3 [16] | i0..i3: w12 (retire oldest slice)
//  i3 epilogue +8 ST, issue O3 -> [24]
//  i4..i6: w20 | i7: w12 (retires ST+O3's pred) | i8: w12, +SQ(8)
//  i9: w16 | i10: w12 | i11: w8 | eud: compiler waits for sq regs.
// STORE=0 path: no ST in queue -> i4..i6 use w12.
template<int STORE>
__global__ __launch_bounds__(256, 2) void stats_kernel(
    const short* __restrict__ Lnp, const short* __restrict__ Obp,
    const float* __restrict__ sq, unsigned* __restrict__ stats,
    unsigned* __restrict__ simT, unsigned* __restrict__ eudT) {
    int bi, bj;
    tile_decode(blockIdx.x, bi, bj);
    int tid = threadIdx.x, lane = tid & 63, wid = tid >> 6;
    int wm = (wid >> 1) * 64, wn = (wid & 1) * 64;
    int wm4 = (wid >> 1) * 4, wn4 = (wid & 1) * 4;
    int l15 = lane & 15, quad = lane >> 4;
    int rB = bi * TILE, cB = bj * TILE;
    int g8 = bi * 8, h8 = bj * 8;
    size_t tB = (size_t)blockIdx.x * 8192 + (size_t)tid * 4;

    __shared__ __align__(16) short As[4][4096];
    __shared__ __align__(16) short Bs[4][4096];
    __shared__ float red[3][4];

    float lmin = 1e30f, lmax = -1e30f, dmax = 0.f;
    f32x4 acc[4][4];

    // ---- prologue: all 4 label slices in flight ----
    zero_acc(acc);
    stage32<16>(Lnp, g8, 0,  &As[0][0], tid); stage32<16>(Lnp, h8, 0,  &Bs[0][0], tid);
    stage32<16>(Lnp, g8, 4,  &As[1][0], tid); stage32<16>(Lnp, h8, 4,  &Bs[1][0], tid);
    stage32<16>(Lnp, g8, 8,  &As[2][0], tid); stage32<16>(Lnp, h8, 8,  &Bs[2][0], tid);
    stage32<16>(Lnp, g8, 12, &As[3][0], tid); stage32<16>(Lnp, h8, 12, &Bs[3][0], tid);

    // i0..i2: labels slices 0-2, refill with outputs slices 0-2
    VMCNT(12); BAR();
    mfma_slice32(&As[0][0], &Bs[0][0], wm4, wn4, l15, quad, acc);
    BAR();
    stage32<32>(Obp, g8, 0, &As[0][0], tid); stage32<32>(Obp, h8, 0, &Bs[0][0], tid);
    VMCNT(12); BAR();
    mfma_slice32(&As[1][0], &Bs[1][0], wm4, wn4, l15, quad, acc);
    BAR();
    stage32<32>(Obp, g8, 4, &As[1][0], tid); stage32<32>(Obp, h8, 4, &Bs[1][0], tid);
    VMCNT(12); BAR();
    mfma_slice32(&As[2][0], &Bs[2][0], wm4, wn4, l15, quad, acc);
    BAR();
    stage32<32>(Obp, g8, 8, &As[2][0], tid); stage32<32>(Obp, h8, 8, &Bs[2][0], tid);

    // i3: last label slice; sim epilogue; refill buf3 with O3
    VMCNT(12); BAR();
    mfma_slice32(&As[3][0], &Bs[3][0], wm4, wn4, l15, quad, acc);
    FENCE();
    #pragma unroll
    for (int mi = 0; mi < 4; mi++) {
        u32x4 v0, v1;
        #pragma unroll
        for (int ni = 0; ni < 4; ni++)
            #pragma unroll
            for (int h = 0; h < 2; h++) {
                float s0 = acc[mi][ni][2 * h], s1 = acc[mi][ni][2 * h + 1];
                lmin = fminf(lmin, fminf(s0, s1));
                lmax = fmaxf(lmax, fmaxf(s0, s1));
                int j = ni * 2 + h;
                unsigned pk = pack2(s0, s1);
                if (j < 4) v0[j] = pk; else v1[j - 4] = pk;
            }
        if (STORE) {
            __builtin_nontemporal_store(v0, (u32x4*)(simT + tB + (mi * 2 + 0) * 1024));
            __builtin_nontemporal_store(v1, (u32x4*)(simT + tB + (mi * 2 + 1) * 1024));
        }
    }
    FENCE();
    BAR();
    stage32<32>(Obp, g8, 12, &As[3][0], tid); stage32<32>(Obp, h8, 12, &Bs[3][0], tid);
    zero_acc(acc);

    // i4..i6: outputs slices 0-2, refill with outputs slices 4-6
    if (STORE) { VMCNT(20); } else { VMCNT(12); }
    BAR();
    mfma_slice32(&As[0][0], &Bs[0][0], wm4, wn4, l15, quad, acc);
    BAR();
    stage32<32>(Obp, g8, 16, &As[0][0], tid); stage32<32>(Obp, h8, 16, &Bs[0][0], tid);
    if (STORE) { VMCNT(20); } else { VMCNT(12); }
    BAR();
    mfma_slice32(&As[1][0], &Bs[1][0], wm4, wn4, l15, quad, acc);
    BAR();
    stage32<32>(Obp, g8, 20, &As[1][0], tid); stage32<32>(Obp, h8, 20, &Bs[1][0], tid);
    if (STORE) { VMCNT(20); } else { VMCNT(12); }
    BAR();
    mfma_slice32(&As[2][0], &Bs[2][0], wm4, wn4, l15, quad, acc);
    BAR();
    stage32<32>(Obp, g8, 24, &As[2][0], tid); stage32<32>(Obp, h8, 24, &Bs[2][0], tid);

    // i7: outputs slice 3, refill buf3 with O7 (last)
    VMCNT(12); BAR();
    mfma_slice32(&As[3][0], &Bs[3][0], wm4, wn4, l15, quad, acc);
    BAR();
    stage32<32>(Obp, g8, 28, &As[3][0], tid); stage32<32>(Obp, h8, 28, &Bs[3][0], tid);

    // i8: outputs slice 4; issue sq loads after (pinned by VMCNTs)
    VMCNT(12); BAR();
    mfma_slice32(&As[0][0], &Bs[0][0], wm4, wn4, l15, quad, acc);
    BAR();
    float sqj[4]; f32x4 sqi4[4];
    #pragma unroll
    for (int ni = 0; ni < 4; ni++) sqj[ni] = sq[cB + wn + ni * 16 + l15];
    #pragma unroll
    for (int mi = 0; mi < 4; mi++)
        sqi4[mi] = *(const f32x4*)&sq[rB + wm + mi * 16 + quad * 4];
    // i9..i11: outputs slices 5-7
    VMCNT(16); BAR();
    mfma_slice32(&As[1][0], &Bs[1][0], wm4, wn4, l15, quad, acc);
    BAR();
    VMCNT(12); BAR();
    mfma_slice32(&As[2][0], &Bs[2][0], wm4, wn4, l15, quad, acc);
    BAR();
    VMCNT(8); BAR();
    mfma_slice32(&As[3][0], &Bs[3][0], wm4, wn4, l15, quad, acc);

    // ---- eud epilogue (compiler inserts waits for sq registers) ----
    #pragma unroll
    for (int mi = 0; mi < 4; mi++) {
        f32x4 sqi = sqi4[mi];
        u32x4 v0, v1;
        #pragma unroll
        for (int ni = 0; ni < 4; ni++)
            #pragma unroll
            for (int h = 0; h < 2; h++) {
                float d20 = fmaxf(sqi[2*h]   + sqj[ni] - 2.f * acc[mi][ni][2*h],   0.f);
                float d21 = fmaxf(sqi[2*h+1] + sqj[ni] - 2.f * acc[mi][ni][2*h+1], 0.f);
                dmax = fmaxf(dmax, fmaxf(d20, d21));
                float e0 = (d20 > 0.f) ? sqrtf(d20) : 0.f;
                float e1 = (d21 > 0.f) ? sqrtf(d21) : 0.f;
                int j = ni * 2 + h;
                unsigned pk = pack2(e0, e1);
                if (j < 4) v0[j] = pk; else v1[j - 4] = pk;
            }
        if (STORE) {
            __builtin_nontemporal_store(v0, (u32x4*)(eudT + tB + (mi * 2 + 0) * 1024));
            __builtin_nontemporal_store(v1, (u32x4*)(eudT + tB + (mi * 2 + 1) * 1024));
        }
    }

    // ---- reductions ----
    #pragma unroll
    for (int m = 1; m < 64; m <<= 1) {
        lmin = fminf(lmin, __shfl_xor(lmin, m));
        lmax = fmaxf(lmax, __shfl_xor(lmax, m));
        dmax = fmaxf(dmax, __shfl_xor(dmax, m));
    }
    if ((tid & 63) == 0) { red[0][wid] = lmin; red[1][wid] = lmax; red[2][wid] = dmax; }
    __syncthreads();
    if (tid == 0) {
        lmin = fminf(fminf(red[0][0], red[0][1]), fminf(red[0][2], red[0][3]));
        lmax = fmaxf(fmaxf(red[1][0], red[1][1]), fmaxf(red[1][2], red[1][3]));
        dmax = fmaxf(fmaxf(red[2][0], red[2][1]), fmaxf(red[2][2], red[2][3]));
        atomicMin(&stats[0], fenc(lmin));
        atomicMax(&stats[1], fenc(lmax));
        atomicMax(&stats[2], fenc(dmax));
    }
}

// ----------------------------------------------------------- loss stream ----
// Pure streaming epilogue (r7-verified): coalesced NT dwordx4 reads,
// exp terms, row+col sums, one atomic per row per block.
__global__ __launch_bounds__(256) void loss_stream_kernel(
    const unsigned* __restrict__ simT, const unsigned* __restrict__ eudT,
    const unsigned* __restrict__ stats,
    float* __restrict__ pos_sums, float* __restrict__ neg_sums) {
    int bi, bj;
    tile_decode(blockIdx.x, bi, bj);
    int tid = threadIdx.x, lane = tid & 63, wid = tid >> 6;
    int wm = (wid >> 1) * 64, wn = (wid & 1) * 64;
    int l15 = lane & 15, quad = lane >> 4;
    size_t tB = (size_t)blockIdx.x * 8192 + (size_t)tid * 4;

    float smin = fdec(stats[0]);
    float smax = fdec(stats[1]);
    float d2max = fdec(stats[2]);
    float invr = 1.f / (smax - smin);
    float invem = rsqrtf(d2max);

    __shared__ float rP[TILE][2], rN[TILE][2];
    __shared__ float cP[TILE][2], cN[TILE][2];
    float cpsum[4] = {0.f, 0.f, 0.f, 0.f};
    float cnsum[4] = {0.f, 0.f, 0.f, 0.f};

    #pragma unroll
    for (int mi = 0; mi < 4; mi++) {
        u32x4 s0 = __builtin_nontemporal_load((const u32x4*)(simT + tB + (mi * 2 + 0) * 1024));
        u32x4 s1 = __builtin_nontemporal_load((const u32x4*)(simT + tB + (mi * 2 + 1) * 1024));
        u32x4 e0 = __builtin_nontemporal_load((const u32x4*)(eudT + tB + (mi * 2 + 0) * 1024));
        u32x4 e1 = __builtin_nontemporal_load((const u32x4*)(eudT + tB + (mi * 2 + 1) * 1024));
        float ps[4] = {0.f, 0.f, 0.f, 0.f};
        float ns[4] = {0.f, 0.f, 0.f, 0.f};
        #pragma unroll
        for (int j = 0; j < 8; j++) {
            unsigned sv = (j < 4) ? s0[j] : s1[j - 4];
            unsigned ev = (j < 4) ? e0[j] : e1[j - 4];
            int ni = j >> 1, h = j & 1;
            f16x2 spair = *(f16x2*)&sv;
            f16x2 epair = *(f16x2*)&ev;
            #pragma unroll
            for (int e = 0; e < 2; e++) {
                float sn = ((float)spair[e] - smin) * invr;
                float dist = (float)epair[e] * invem + sn;
                bool pos = sn > 0.5f;   // TAU
                float pv = pos ? __expf(dist) : 0.f;
                float nv = pos ? 0.f : __expf(1.0f - dist);  // MAG = 1
                ps[2 * h + e] += pv;  ns[2 * h + e] += nv;
                cpsum[ni] += pv;  cnsum[ni] += nv;
            }
        }
        #pragma unroll
        for (int r = 0; r < 4; r++) {
            #pragma unroll
            for (int m = 1; m < 16; m <<= 1) {
                ps[r] += __shfl_xor(ps[r], m);
                ns[r] += __shfl_xor(ns[r], m);
            }
            if (l15 == 0) {
                int rr = wm + mi * 16 + quad * 4 + r;
                rP[rr][wid & 1] = ps[r];
                rN[rr][wid & 1] = ns[r];
            }
        }
    }
    #pragma unroll
    for (int ni = 0; ni < 4; ni++) {
        #pragma unroll
        for (int m = 16; m < 64; m <<= 1) {
            cpsum[ni] += __shfl_xor(cpsum[ni], m);
            cnsum[ni] += __shfl_xor(cnsum[ni], m);
        }
        if (quad == 0) {
            int cc = wn + ni * 16 + l15;
            cP[cc][wid >> 1] = cpsum[ni];
            cN[cc][wid >> 1] = cnsum[ni];
        }
    }
    __syncthreads();
    if (tid < TILE) {
        atomicAdd(&pos_sums[bi * TILE + tid], rP[tid][0] + rP[tid][1]);
        atomicAdd(&neg_sums[bi * TILE + tid], rN[tid][0] + rN[tid][1]);
        if (bi != bj) {
            atomicAdd(&pos_sums[bj * TILE + tid], cP[tid][0] + cP[tid][1]);
            atomicAdd(&neg_sums[bj * TILE + tid], cN[tid][0] + cN[tid][1]);
        }
    }
}

// ------------------------------------------ loss fallback (recompute, r18) ----
__global__ __launch_bounds__(256, 2) void loss_recompute_kernel(
    const short* __restrict__ Lnp, const short* __restrict__ Obp,
    const float* __restrict__ sq, const unsigned* __restrict__ stats,
    float* __restrict__ pos_sums, float* __restrict__ neg_sums) {
    int bi, bj;
    tile_decode(blockIdx.x, bi, bj);
    int tid = threadIdx.x, lane = tid & 63, wid = tid >> 6;
    int wm = (wid >> 1) * 64, wn = (wid & 1) * 64;
    int wm4 = (wid >> 1) * 4, wn4 = (wid & 1) * 4;
    int l15 = lane & 15, quad = lane >> 4;
    int rB = bi * TILE, cB = bj * TILE;

    __shared__ __align__(16) short As[1024 * 8];
    __shared__ __align__(16) short Bs[1024 * 8];
    __shared__ unsigned simW[256 * 33];
    __shared__ float rP[TILE][2], rN[TILE][2];
    __shared__ float cP[TILE][2], cN[TILE][2];
    unsigned* my = &simW[tid * 33];

    f32x4 acc[4][4];

    zero_acc(acc);
    gram_staged<16, 2>(Lnp, bi * 8, bj * 8, As, Bs, tid, wm4, wn4, l15, quad, acc);
    #pragma unroll
    for (int mi = 0; mi < 4; mi++)
        #pragma unroll
        for (int ni = 0; ni < 4; ni++) {
            my[(mi * 4 + ni) * 2 + 0] = pack2(acc[mi][ni][0], acc[mi][ni][1]);
            my[(mi * 4 + ni) * 2 + 1] = pack2(acc[mi][ni][2], acc[mi][ni][3]);
        }

    zero_acc(acc);
    gram_staged<32, 4>(Obp, bi * 8, bj * 8, As, Bs, tid, wm4, wn4, l15, quad, acc);

    float smin = fdec(stats[0]);
    float smax = fdec(stats[1]);
    float d2max = fdec(stats[2]);
    float invr = 1.f / (smax - smin);
    float invem = rsqrtf(d2max);

    float sqj[4];
    #pragma unroll
    for (int ni = 0; ni < 4; ni++) sqj[ni] = sq[cB + wn + ni * 16 + l15];
    float cpsum[4] = {0.f, 0.f, 0.f, 0.f};
    float cnsum[4] = {0.f, 0.f, 0.f, 0.f};

    #pragma unroll
    for (int mi = 0; mi < 4; mi++) {
        f32x4 sqi = *(const f32x4*)&sq[rB + wm + mi * 16 + quad * 4];
        float ps[4] = {0.f, 0.f, 0.f, 0.f};
        float ns[4] = {0.f, 0.f, 0.f, 0.f};
        #pragma unroll
        for (int ni = 0; ni < 4; ni++) {
            f16x2 s01 = ((const f16x2*)my)[(mi * 4 + ni) * 2 + 0];
            f16x2 s23 = ((const f16x2*)my)[(mi * 4 + ni) * 2 + 1];
            #pragma unroll
            for (int r = 0; r < 4; r++) {
                float sraw = (r < 2) ? (float)s01[r] : (float)s23[r - 2];
                float sn = (sraw - smin) * invr;
                float g = acc[mi][ni][r];
                float d2 = fmaxf(sqi[r] + sqj[ni] - 2.f * g, 0.f);
                float eud = (d2 > 0.f) ? sqrtf(d2) * invem : 0.f;
                float dist = eud + sn;
                bool pos = sn > 0.5f;
                float pv = pos ? __expf(dist) : 0.f;
                float nv = pos ? 0.f : __expf(1.0f - dist);
                ps[r] += pv;  ns[r] += nv;
                cpsum[ni] += pv;  cnsum[ni] += nv;
            }
        }
        #pragma unroll
        for (int r = 0; r < 4; r++) {
            #pragma unroll
            for (int m = 1; m < 16; m <<= 1) {
                ps[r] += __shfl_xor(ps[r], m);
                ns[r] += __shfl_xor(ns[r], m);
            }
            if (l15 == 0) {
                int rr = wm + mi * 16 + quad * 4 + r;
                rP[rr][wid & 1] = ps[r];
                rN[rr][wid & 1] = ns[r];
            }
        }
    }
    #pragma unroll
    for (int ni = 0; ni < 4; ni++) {
        #pragma unroll
        for (int m = 16; m < 64; m <<= 1) {
            cpsum[ni] += __shfl_xor(cpsum[ni], m);
            cnsum[ni] += __shfl_xor(cnsum[ni], m);
        }
        if (quad == 0) {
            int cc = wn + ni * 16 + l15;
            cP[cc][wid >> 1] = cpsum[ni];
            cN[cc][wid >> 1] = cnsum[ni];
        }
    }
    __syncthreads();
    if (tid < TILE) {
        atomicAdd(&pos_sums[bi * TILE + tid], rP[tid][0] + rP[tid][1]);
        atomicAdd(&neg_sums[bi * TILE + tid], rN[tid][0] + rN[tid][1]);
        if (bi != bj) {
            atomicAdd(&pos_sums[bj * TILE + tid], cP[tid][0] + cP[tid][1]);
            atomicAdd(&neg_sums[bj * TILE + tid], cN[tid][0] + cN[tid][1]);
        }
    }
}

// ------------------------------------------------------------- finalize ----
__global__ __launch_bounds__(256) void finalize_kernel(
    const float* __restrict__ pos_sums, const float* __restrict__ neg_sums,
    float* __restrict__ out) {
    int t = threadIdx.x;
    float acc = 0.f;
    for (int i = t; i < B_N; i += 256) {
        float p = pos_sums[i], n = neg_sums[i];
        float pl = fmaxf(logf(p), 0.f);
        float nl = (n > 0.f) ? fmaxf(logf(n), 0.f) : 0.f;
        acc += pl + nl;
    }
    #pragma unroll
    for (int m = 1; m < 64; m <<= 1) acc += __shfl_xor(acc, m);
    __shared__ float w4[4];
    if ((t & 63) == 0) w4[t >> 6] = acc;
    __syncthreads();
    if (t == 0) out[0] = (w4[0] + w4[1] + w4[2] + w4[3]) / (float)B_N;
}

// ------------------------------------------------------------------ entry ----
extern "C" void kernel_launch(void* const* d_in, const int* in_sizes, int n_in,
                              void* d_out, int out_size, void* d_ws, size_t ws_size,
                              hipStream_t stream) {
    const float* outputs = (const float*)d_in[0];
    const float* labels  = (const float*)d_in[1];
    float* out = (float*)d_out;
    char* ws = (char*)d_ws;
    __hip_bfloat16* Obp = (__hip_bfloat16*)(ws);
    __hip_bfloat16* Lnp = (__hip_bfloat16*)(ws + 4194304);
    float* sq           = (float*)(ws + 6291456);
    float* pos_sums     = (float*)(ws + 6324224);
    float* neg_sums     = (float*)(ws + 6356992);
    unsigned* stats     = (unsigned*)(ws + 6389760);
    unsigned* simT      = (unsigned*)(ws + 6389824);
    unsigned* eudT      = (unsigned*)(ws + 74547264);
    int big = (ws_size >= WS_NEEDED) ? 1 : 0;

    prep_kernel<<<B_N / 16, 256, 0, stream>>>(outputs, labels, Obp, Lnp, sq,
                                              pos_sums, neg_sums, stats);
    if (big) {
        stats_kernel<1><<<NTRI, 256, 0, stream>>>((const short*)Lnp,
                                                  (const short*)Obp,
                                                  sq, stats, simT, eudT);
        loss_stream_kernel<<<NTRI, 256, 0, stream>>>(simT, eudT, stats,
                                                     pos_sums, neg_sums);
    } else {
        stats_kernel<0><<<NTRI, 256, 0, stream>>>((const short*)Lnp,
                                                  (const short*)Obp,
                                                  sq, stats, simT, eudT);
        loss_recompute_kernel<<<NTRI, 256, 0, stream>>>((const short*)Lnp,
                                                        (const short*)Obp,
                                                        sq, stats,
                                                        pos_sums, neg_sums);
    }
    finalize_kernel<<<1, 256, 0, stream>>>(pos_sums, neg_sums, out);
}

// Round 9
// 206.087 us; speedup vs baseline: 1.3006x; 1.0147x over previous
//
#include <hip/hip_runtime.h>
#include <hip/hip_bf16.h>

// WeightedLoss round 28: pivot off stats (pre-committed). r27 closed the
// stats investigation: drain (104) = depth-1 (105.7) = depth-4 (106.8),
// clean counters, occupancy hard-capped at 2 blk/CU by the 156-reg/wave
// working set -> ~105us is the gram-pass floor across ~25 variants.
// Remaining budget: total 209 = stats 107 + ~102 non-stats. Estimates put
// loss_stream at 60-80us, not the assumed 40: its __builtin_nontemporal_
// loads of the 136MB sim/eud round-trip carry the no-allocate hint on the
// READ path -> likely bypassing the Infinity Cache that still holds the
// freshly-written data, forcing HBM reads. r28 = r27 with loss_stream's
// 4 NT loads -> plain loads (single variable, separate kernel, separate
// counters). Stats NT stores kept (protect per-XCD L2 from write-allocate
// thrash against gram panels - validated by r19's 90% L2 hit).
// Read: total drops -> continue on loss side; unchanged -> all components
// at measured floors, declare roofline next round.
// ws: [0] Obp packed 4 MB | [4194304] Lnp packed 2 MB | [6291456] sq
//     [6324224] pos_sums | [6356992] neg_sums | [6389760] stats u32[3]
//     [6389824] simT fp16 2080x16384 (68.2 MB) | [74547264] eudT (68.2 MB)

#define B_N 8192
#define TILE 128
#define NTRI 2080
#define WS_NEEDED 142704704ull

typedef __attribute__((ext_vector_type(8))) short bf16x8;
typedef __attribute__((ext_vector_type(4))) float f32x4;
typedef __attribute__((ext_vector_type(2))) _Float16 f16x2;
typedef __attribute__((ext_vector_type(4))) unsigned u32x4;

typedef const __attribute__((address_space(1))) void g_void;
typedef __attribute__((address_space(3))) void l_void;

__device__ __forceinline__ unsigned fenc(float f) {
    unsigned u = __float_as_uint(f);
    return (u & 0x80000000u) ? ~u : (u | 0x80000000u);
}
__device__ __forceinline__ float fdec(unsigned k) {
    unsigned u = (k & 0x80000000u) ? (k ^ 0x80000000u) : ~k;
    return __uint_as_float(u);
}
__device__ __forceinline__ unsigned pack2(float a, float b) {
    f16x2 p; p[0] = (_Float16)a; p[1] = (_Float16)b;
    return *(unsigned*)&p;
}

// Tile decode for the 64x64 128-tile triangle. bi<=bj always.
__device__ __forceinline__ void tile_decode(int b, int& bi, int& bj) {
    int si, sj, ti, tj;
    if (b < 544) {
        int sb = b / 136, w = b - sb * 136;
        int i = 0;
        while (w >= 16 - i) { w -= 16 - i; i++; }
        si = sb; sj = sb; ti = i; tj = i + w;
    } else {
        int q = (b - 544) >> 8, w = (b - 544) & 255;
        int i = 0;
        while (q >= 3 - i) { q -= 3 - i; i++; }
        si = i; sj = i + 1 + q;
        ti = w >> 4; tj = w & 15;
    }
    bi = si * 16 + ti; bj = sj * 16 + tj;
}

// ---------------------------------------------------------------- prep ----
__global__ __launch_bounds__(256) void prep_kernel(
    const float* __restrict__ outputs, const float* __restrict__ labels,
    __hip_bfloat16* __restrict__ Obp, __hip_bfloat16* __restrict__ Lnp,
    float* __restrict__ sq, float* __restrict__ pos_sums,
    float* __restrict__ neg_sums, unsigned* __restrict__ stats) {
    int g = blockIdx.x, tid = threadIdx.x;
    int rl = tid >> 4, c = tid & 15;
    int row = g * 16 + rl;
    __shared__ __align__(16) short tO[16][264];
    __shared__ __align__(16) short tL[16][136];

    float s = 0.f;
    #pragma unroll
    for (int k = 0; k < 4; k++) {
        f32x4 v = *(const f32x4*)&outputs[(size_t)row * 256 + c * 16 + k * 4];
        s += v[0]*v[0] + v[1]*v[1] + v[2]*v[2] + v[3]*v[3];
        __hip_bfloat16 b4[4];
        #pragma unroll
        for (int i = 0; i < 4; i++) b4[i] = __float2bfloat16(v[i]);
        *(uint2*)&tO[rl][c * 16 + k * 4] = *(uint2*)b4;
    }
    #pragma unroll
    for (int m = 1; m < 16; m <<= 1) s += __shfl_xor(s, m);
    if (c == 0) sq[row] = s;

    float ls = 0.f;
    f32x4 u0 = *(const f32x4*)&labels[(size_t)row * 128 + c * 8];
    f32x4 u1 = *(const f32x4*)&labels[(size_t)row * 128 + c * 8 + 4];
    ls += u0[0]*u0[0] + u0[1]*u0[1] + u0[2]*u0[2] + u0[3]*u0[3];
    ls += u1[0]*u1[0] + u1[1]*u1[1] + u1[2]*u1[2] + u1[3]*u1[3];
    #pragma unroll
    for (int m = 1; m < 16; m <<= 1) ls += __shfl_xor(ls, m);
    float inv = 1.f / (sqrtf(ls) + 1e-12f);
    {
        __hip_bfloat16 b4[4];
        #pragma unroll
        for (int i = 0; i < 4; i++) b4[i] = __float2bfloat16(u0[i] * inv);
        *(uint2*)&tL[rl][c * 8] = *(uint2*)b4;
        #pragma unroll
        for (int i = 0; i < 4; i++) b4[i] = __float2bfloat16(u1[i] * inv);
        *(uint2*)&tL[rl][c * 8 + 4] = *(uint2*)b4;
    }
    if (tid < 16) { pos_sums[g * 16 + tid] = 0.f; neg_sums[g * 16 + tid] = 0.f; }
    if (g == 0 && tid == 0) {
        stats[0] = 0xFFFFFFFFu; stats[1] = 0u; stats[2] = 0u;
    }
    __syncthreads();

    #pragma unroll
    for (int q = 0; q < 2; q++) {
        int sl = tid * 2 + q;
        int o = sl >> 4, rr = sl & 15;
        uint4 d = *(uint4*)&tO[rr][o * 8];
        *(uint4*)&Obp[(size_t)g * 4096 + (size_t)sl * 8] = d;
    }
    {
        int o = tid >> 4, rr = tid & 15;
        uint4 d = *(uint4*)&tL[rr][o * 8];
        *(uint4*)&Lnp[(size_t)g * 2048 + (size_t)tid * 8] = d;
    }
}

// ------------------------------------------------- staged slice gram ----
// (64-K helpers kept for the loss_recompute fallback)
template<int KD8>
__device__ __forceinline__ void stage_slice(
    const short* __restrict__ P, int g0, int o0, short* L, int tid) {
    #pragma unroll
    for (int p = 0; p < 4; p++) {
        int u = p * 256 + tid;
        int gl = u >> 7, off = u & 127;
        size_t gu = ((size_t)(g0 + gl) * KD8 + o0) * 16 + off;
        __builtin_amdgcn_global_load_lds((g_void*)(P + gu * 8),
                                         (l_void*)(L + (size_t)u * 8), 16, 0, 0);
    }
}

__device__ __forceinline__ void mfma_slice(
    const short* As, const short* Bs, int wm4, int wn4,
    int l15, int quad, f32x4 (&acc)[4][4]) {
    #pragma unroll
    for (int kc = 0; kc < 2; kc++) {
        bf16x8 a[4], b[4];
        #pragma unroll
        for (int mi = 0; mi < 4; mi++)
            a[mi] = *(const bf16x8*)&As[((wm4 + mi) * 128
                                         + (kc * 4 + quad) * 16 + l15) * 8];
        #pragma unroll
        for (int ni = 0; ni < 4; ni++)
            b[ni] = *(const bf16x8*)&Bs[((wn4 + ni) * 128
                                         + (kc * 4 + quad) * 16 + l15) * 8];
        #pragma unroll
        for (int mi = 0; mi < 4; mi++)
            #pragma unroll
            for (int ni = 0; ni < 4; ni++)
                acc[mi][ni] = __builtin_amdgcn_mfma_f32_16x16x32_bf16(
                    a[mi], b[ni], acc[mi][ni], 0, 0, 0);
    }
}

__device__ __forceinline__ void zero_acc(f32x4 (&acc)[4][4]) {
    #pragma unroll
    for (int mi = 0; mi < 4; mi++)
        #pragma unroll
        for (int ni = 0; ni < 4; ni++) {
            f32x4 z = {0.f, 0.f, 0.f, 0.f};
            acc[mi][ni] = z;
        }
}

template<int KD8, int NS>
__device__ __forceinline__ void gram_staged(
    const short* __restrict__ P, int gA0, int gB0,
    short* As, short* Bs, int tid, int wm4, int wn4,
    int l15, int quad, f32x4 (&acc)[4][4]) {
    #pragma unroll
    for (int s = 0; s < NS; s++) {
        __syncthreads();
        stage_slice<KD8>(P, gA0, s * 8, As, tid);
        stage_slice<KD8>(P, gB0, s * 8, Bs, tid);
        __syncthreads();
        mfma_slice(As, Bs, wm4, wn4, l15, quad, acc);
    }
}

// ---- 32-K slice machinery (r27 stats pipeline) ----
template<int KD8>
__device__ __forceinline__ void stage32(const short* __restrict__ P, int g0,
                                        int ko8, short* L, int tid) {
    #pragma unroll
    for (int p = 0; p < 2; p++) {
        int u = p * 256 + tid;
        int gl = u >> 6, k8l = (u >> 4) & 3, r = u & 15;
        size_t gu = ((size_t)(g0 + gl) * KD8 + ko8 + k8l) * 16 + r;
        __builtin_amdgcn_global_load_lds((g_void*)(P + gu * 8),
                                         (l_void*)(L + (size_t)u * 8), 16, 0, 0);
    }
}

__device__ __forceinline__ void mfma_slice32(
    const short* As, const short* Bs, int wm4, int wn4,
    int l15, int quad, f32x4 (&acc)[4][4]) {
    bf16x8 a[4], b[4];
    #pragma unroll
    for (int mi = 0; mi < 4; mi++)
        a[mi] = *(const bf16x8*)&As[((wm4 + mi) * 64 + quad * 16 + l15) * 8];
    #pragma unroll
    for (int ni = 0; ni < 4; ni++)
        b[ni] = *(const bf16x8*)&Bs[((wn4 + ni) * 64 + quad * 16 + l15) * 8];
    #pragma unroll
    for (int mi = 0; mi < 4; mi++)
        #pragma unroll
        for (int ni = 0; ni < 4; ni++)
            acc[mi][ni] = __builtin_amdgcn_mfma_f32_16x16x32_bf16(
                a[mi], b[ni], acc[mi][ni], 0, 0, 0);
}

#define VMCNT(n) asm volatile("s_waitcnt vmcnt(" #n ")" ::: "memory")
#define BAR() __builtin_amdgcn_s_barrier()
#define FENCE() asm volatile("" ::: "memory")

// ---------------------------------------------------------------- stats ----
// r19 geometry + 12x 32-K slices, 4 buffers resident (depth-4 prefetch).
// Verified r27 schedule, unchanged.
template<int STORE>
__global__ __launch_bounds__(256, 2) void stats_kernel(
    const short* __restrict__ Lnp, const short* __restrict__ Obp,
    const float* __restrict__ sq, unsigned* __restrict__ stats,
    unsigned* __restrict__ simT, unsigned* __restrict__ eudT) {
    int bi, bj;
    tile_decode(blockIdx.x, bi, bj);
    int tid = threadIdx.x, lane = tid & 63, wid = tid >> 6;
    int wm = (wid >> 1) * 64, wn = (wid & 1) * 64;
    int wm4 = (wid >> 1) * 4, wn4 = (wid & 1) * 4;
    int l15 = lane & 15, quad = lane >> 4;
    int rB = bi * TILE, cB = bj * TILE;
    int g8 = bi * 8, h8 = bj * 8;
    size_t tB = (size_t)blockIdx.x * 8192 + (size_t)tid * 4;

    __shared__ __align__(16) short As[4][4096];
    __shared__ __align__(16) short Bs[4][4096];
    __shared__ float red[3][4];

    float lmin = 1e30f, lmax = -1e30f, dmax = 0.f;
    f32x4 acc[4][4];

    // ---- prologue: all 4 label slices in flight ----
    zero_acc(acc);
    stage32<16>(Lnp, g8, 0,  &As[0][0], tid); stage32<16>(Lnp, h8, 0,  &Bs[0][0], tid);
    stage32<16>(Lnp, g8, 4,  &As[1][0], tid); stage32<16>(Lnp, h8, 4,  &Bs[1][0], tid);
    stage32<16>(Lnp, g8, 8,  &As[2][0], tid); stage32<16>(Lnp, h8, 8,  &Bs[2][0], tid);
    stage32<16>(Lnp, g8, 12, &As[3][0], tid); stage32<16>(Lnp, h8, 12, &Bs[3][0], tid);

    // i0..i2: labels slices 0-2, refill with outputs slices 0-2
    VMCNT(12); BAR();
    mfma_slice32(&As[0][0], &Bs[0][0], wm4, wn4, l15, quad, acc);
    BAR();
    stage32<32>(Obp, g8, 0, &As[0][0], tid); stage32<32>(Obp, h8, 0, &Bs[0][0], tid);
    VMCNT(12); BAR();
    mfma_slice32(&As[1][0], &Bs[1][0], wm4, wn4, l15, quad, acc);
    BAR();
    stage32<32>(Obp, g8, 4, &As[1][0], tid); stage32<32>(Obp, h8, 4, &Bs[1][0], tid);
    VMCNT(12); BAR();
    mfma_slice32(&As[2][0], &Bs[2][0], wm4, wn4, l15, quad, acc);
    BAR();
    stage32<32>(Obp, g8, 8, &As[2][0], tid); stage32<32>(Obp, h8, 8, &Bs[2][0], tid);

    // i3: last label slice; sim epilogue; refill buf3 with O3
    VMCNT(12); BAR();
    mfma_slice32(&As[3][0], &Bs[3][0], wm4, wn4, l15, quad, acc);
    FENCE();
    #pragma unroll
    for (int mi = 0; mi < 4; mi++) {
        u32x4 v0, v1;
        #pragma unroll
        for (int ni = 0; ni < 4; ni++)
            #pragma unroll
            for (int h = 0; h < 2; h++) {
                float s0 = acc[mi][ni][2 * h], s1 = acc[mi][ni][2 * h + 1];
                lmin = fminf(lmin, fminf(s0, s1));
                lmax = fmaxf(lmax, fmaxf(s0, s1));
                int j = ni * 2 + h;
                unsigned pk = pack2(s0, s1);
                if (j < 4) v0[j] = pk; else v1[j - 4] = pk;
            }
        if (STORE) {
            __builtin_nontemporal_store(v0, (u32x4*)(simT + tB + (mi * 2 + 0) * 1024));
            __builtin_nontemporal_store(v1, (u32x4*)(simT + tB + (mi * 2 + 1) * 1024));
        }
    }
    FENCE();
    BAR();
    stage32<32>(Obp, g8, 12, &As[3][0], tid); stage32<32>(Obp, h8, 12, &Bs[3][0], tid);
    zero_acc(acc);

    // i4..i6: outputs slices 0-2, refill with outputs slices 4-6
    if (STORE) { VMCNT(20); } else { VMCNT(12); }
    BAR();
    mfma_slice32(&As[0][0], &Bs[0][0], wm4, wn4, l15, quad, acc);
    BAR();
    stage32<32>(Obp, g8, 16, &As[0][0], tid); stage32<32>(Obp, h8, 16, &Bs[0][0], tid);
    if (STORE) { VMCNT(20); } else { VMCNT(12); }
    BAR();
    mfma_slice32(&As[1][0], &Bs[1][0], wm4, wn4, l15, quad, acc);
    BAR();
    stage32<32>(Obp, g8, 20, &As[1][0], tid); stage32<32>(Obp, h8, 20, &Bs[1][0], tid);
    if (STORE) { VMCNT(20); } else { VMCNT(12); }
    BAR();
    mfma_slice32(&As[2][0], &Bs[2][0], wm4, wn4, l15, quad, acc);
    BAR();
    stage32<32>(Obp, g8, 24, &As[2][0], tid); stage32<32>(Obp, h8, 24, &Bs[2][0], tid);

    // i7: outputs slice 3, refill buf3 with O7 (last)
    VMCNT(12); BAR();
    mfma_slice32(&As[3][0], &Bs[3][0], wm4, wn4, l15, quad, acc);
    BAR();
    stage32<32>(Obp, g8, 28, &As[3][0], tid); stage32<32>(Obp, h8, 28, &Bs[3][0], tid);

    // i8: outputs slice 4; issue sq loads after (pinned by VMCNTs)
    VMCNT(12); BAR();
    mfma_slice32(&As[0][0], &Bs[0][0], wm4, wn4, l15, quad, acc);
    BAR();
    float sqj[4]; f32x4 sqi4[4];
    #pragma unroll
    for (int ni = 0; ni < 4; ni++) sqj[ni] = sq[cB + wn + ni * 16 + l15];
    #pragma unroll
    for (int mi = 0; mi < 4; mi++)
        sqi4[mi] = *(const f32x4*)&sq[rB + wm + mi * 16 + quad * 4];
    // i9..i11: outputs slices 5-7
    VMCNT(16); BAR();
    mfma_slice32(&As[1][0], &Bs[1][0], wm4, wn4, l15, quad, acc);
    BAR();
    VMCNT(12); BAR();
    mfma_slice32(&As[2][0], &Bs[2][0], wm4, wn4, l15, quad, acc);
    BAR();
    VMCNT(8); BAR();
    mfma_slice32(&As[3][0], &Bs[3][0], wm4, wn4, l15, quad, acc);

    // ---- eud epilogue (compiler inserts waits for sq registers) ----
    #pragma unroll
    for (int mi = 0; mi < 4; mi++) {
        f32x4 sqi = sqi4[mi];
        u32x4 v0, v1;
        #pragma unroll
        for (int ni = 0; ni < 4; ni++)
            #pragma unroll
            for (int h = 0; h < 2; h++) {
                float d20 = fmaxf(sqi[2*h]   + sqj[ni] - 2.f * acc[mi][ni][2*h],   0.f);
                float d21 = fmaxf(sqi[2*h+1] + sqj[ni] - 2.f * acc[mi][ni][2*h+1], 0.f);
                dmax = fmaxf(dmax, fmaxf(d20, d21));
                float e0 = (d20 > 0.f) ? sqrtf(d20) : 0.f;
                float e1 = (d21 > 0.f) ? sqrtf(d21) : 0.f;
                int j = ni * 2 + h;
                unsigned pk = pack2(e0, e1);
                if (j < 4) v0[j] = pk; else v1[j - 4] = pk;
            }
        if (STORE) {
            __builtin_nontemporal_store(v0, (u32x4*)(eudT + tB + (mi * 2 + 0) * 1024));
            __builtin_nontemporal_store(v1, (u32x4*)(eudT + tB + (mi * 2 + 1) * 1024));
        }
    }

    // ---- reductions ----
    #pragma unroll
    for (int m = 1; m < 64; m <<= 1) {
        lmin = fminf(lmin, __shfl_xor(lmin, m));
        lmax = fmaxf(lmax, __shfl_xor(lmax, m));
        dmax = fmaxf(dmax, __shfl_xor(dmax, m));
    }
    if ((tid & 63) == 0) { red[0][wid] = lmin; red[1][wid] = lmax; red[2][wid] = dmax; }
    __syncthreads();
    if (tid == 0) {
        lmin = fminf(fminf(red[0][0], red[0][1]), fminf(red[0][2], red[0][3]));
        lmax = fmaxf(fmaxf(red[1][0], red[1][1]), fmaxf(red[1][2], red[1][3]));
        dmax = fmaxf(fmaxf(red[2][0], red[2][1]), fmaxf(red[2][2], red[2][3]));
        atomicMin(&stats[0], fenc(lmin));
        atomicMax(&stats[1], fenc(lmax));
        atomicMax(&stats[2], fenc(dmax));
    }
}

// ----------------------------------------------------------- loss stream ----
// r28: PLAIN loads (was NT). The 136MB sim/eud data was just written and
// lives in the 256MB Infinity Cache; the nt no-allocate hint on loads
// plausibly forced HBM reads. Plain dwordx4 loads let L2/L3 serve them.
__global__ __launch_bounds__(256) void loss_stream_kernel(
    const unsigned* __restrict__ simT, const unsigned* __restrict__ eudT,
    const unsigned* __restrict__ stats,
    float* __restrict__ pos_sums, float* __restrict__ neg_sums) {
    int bi, bj;
    tile_decode(blockIdx.x, bi, bj);
    int tid = threadIdx.x, lane = tid & 63, wid = tid >> 6;
    int wm = (wid >> 1) * 64, wn = (wid & 1) * 64;
    int l15 = lane & 15, quad = lane >> 4;
    size_t tB = (size_t)blockIdx.x * 8192 + (size_t)tid * 4;

    float smin = fdec(stats[0]);
    float smax = fdec(stats[1]);
    float d2max = fdec(stats[2]);
    float invr = 1.f / (smax - smin);
    float invem = rsqrtf(d2max);

    __shared__ float rP[TILE][2], rN[TILE][2];
    __shared__ float cP[TILE][2], cN[TILE][2];
    float cpsum[4] = {0.f, 0.f, 0.f, 0.f};
    float cnsum[4] = {0.f, 0.f, 0.f, 0.f};

    #pragma unroll
    for (int mi = 0; mi < 4; mi++) {
        u32x4 s0 = *(const u32x4*)(simT + tB + (mi * 2 + 0) * 1024);
        u32x4 s1 = *(const u32x4*)(simT + tB + (mi * 2 + 1) * 1024);
        u32x4 e0 = *(const u32x4*)(eudT + tB + (mi * 2 + 0) * 1024);
        u32x4 e1 = *(const u32x4*)(eudT + tB + (mi * 2 + 1) * 1024);
        float ps[4] = {0.f, 0.f, 0.f, 0.f};
        float ns[4] = {0.f, 0.f, 0.f, 0.f};
        #pragma unroll
        for (int j = 0; j < 8; j++) {
            unsigned sv = (j < 4) ? s0[j] : s1[j - 4];
            unsigned ev = (j < 4) ? e0[j] : e1[j - 4];
            int ni = j >> 1, h = j & 1;
            f16x2 spair = *(f16x2*)&sv;
            f16x2 epair = *(f16x2*)&ev;
            #pragma unroll
            for (int e = 0; e < 2; e++) {
                float sn = ((float)spair[e] - smin) * invr;
                float dist = (float)epair[e] * invem + sn;
                bool pos = sn > 0.5f;   // TAU
                float pv = pos ? __expf(dist) : 0.f;
                float nv = pos ? 0.f : __expf(1.0f - dist);  // MAG = 1
                ps[2 * h + e] += pv;  ns[2 * h + e] += nv;
                cpsum[ni] += pv;  cnsum[ni] += nv;
            }
        }
        #pragma unroll
        for (int r = 0; r < 4; r++) {
            #pragma unroll
            for (int m = 1; m < 16; m <<= 1) {
                ps[r] += __shfl_xor(ps[r], m);
                ns[r] += __shfl_xor(ns[r], m);
            }
            if (l15 == 0) {
                int rr = wm + mi * 16 + quad * 4 + r;
                rP[rr][wid & 1] = ps[r];
                rN[rr][wid & 1] = ns[r];
            }
        }
    }
    #pragma unroll
    for (int ni = 0; ni < 4; ni++) {
        #pragma unroll
        for (int m = 16; m < 64; m <<= 1) {
            cpsum[ni] += __shfl_xor(cpsum[ni], m);
            cnsum[ni] += __shfl_xor(cnsum[ni], m);
        }
        if (quad == 0) {
            int cc = wn + ni * 16 + l15;
            cP[cc][wid >> 1] = cpsum[ni];
            cN[cc][wid >> 1] = cnsum[ni];
        }
    }
    __syncthreads();
    if (tid < TILE) {
        atomicAdd(&pos_sums[bi * TILE + tid], rP[tid][0] + rP[tid][1]);
        atomicAdd(&neg_sums[bi * TILE + tid], rN[tid][0] + rN[tid][1]);
        if (bi != bj) {
            atomicAdd(&pos_sums[bj * TILE + tid], cP[tid][0] + cP[tid][1]);
            atomicAdd(&neg_sums[bj * TILE + tid], cN[tid][0] + cN[tid][1]);
        }
    }
}

// ------------------------------------------ loss fallback (recompute, r18) ----
__global__ __launch_bounds__(256, 2) void loss_recompute_kernel(
    const short* __restrict__ Lnp, const short* __restrict__ Obp,
    const float* __restrict__ sq, const unsigned* __restrict__ stats,
    float* __restrict__ pos_sums, float* __restrict__ neg_sums) {
    int bi, bj;
    tile_decode(blockIdx.x, bi, bj);
    int tid = threadIdx.x, lane = tid & 63, wid = tid >> 6;
    int wm = (wid >> 1) * 64, wn = (wid & 1) * 64;
    int wm4 = (wid >> 1) * 4, wn4 = (wid & 1) * 4;
    int l15 = lane & 15, quad = lane >> 4;
    int rB = bi * TILE, cB = bj * TILE;

    __shared__ __align__(16) short As[1024 * 8];
    __shared__ __align__(16) short Bs[1024 * 8];
    __shared__ unsigned simW[256 * 33];
    __shared__ float rP[TILE][2], rN[TILE][2];
    __shared__ float cP[TILE][2], cN[TILE][2];
    unsigned* my = &simW[tid * 33];

    f32x4 acc[4][4];

    zero_acc(acc);
    gram_staged<16, 2>(Lnp, bi * 8, bj * 8, As, Bs, tid, wm4, wn4, l15, quad, acc);
    #pragma unroll
    for (int mi = 0; mi < 4; mi++)
        #pragma unroll
        for (int ni = 0; ni < 4; ni++) {
            my[(mi * 4 + ni) * 2 + 0] = pack2(acc[mi][ni][0], acc[mi][ni][1]);
            my[(mi * 4 + ni) * 2 + 1] = pack2(acc[mi][ni][2], acc[mi][ni][3]);
        }

    zero_acc(acc);
    gram_staged<32, 4>(Obp, bi * 8, bj * 8, As, Bs, tid, wm4, wn4, l15, quad, acc);

    float smin = fdec(stats[0]);
    float smax = fdec(stats[1]);
    float d2max = fdec(stats[2]);
    float invr = 1.f / (smax - smin);
    float invem = rsqrtf(d2max);

    float sqj[4];
    #pragma unroll
    for (int ni = 0; ni < 4; ni++) sqj[ni] = sq[cB + wn + ni * 16 + l15];
    float cpsum[4] = {0.f, 0.f, 0.f, 0.f};
    float cnsum[4] = {0.f, 0.f, 0.f, 0.f};

    #pragma unroll
    for (int mi = 0; mi < 4; mi++) {
        f32x4 sqi = *(const f32x4*)&sq[rB + wm + mi * 16 + quad * 4];
        float ps[4] = {0.f, 0.f, 0.f, 0.f};
        float ns[4] = {0.f, 0.f, 0.f, 0.f};
        #pragma unroll
        for (int ni = 0; ni < 4; ni++) {
            f16x2 s01 = ((const f16x2*)my)[(mi * 4 + ni) * 2 + 0];
            f16x2 s23 = ((const f16x2*)my)[(mi * 4 + ni) * 2 + 1];
            #pragma unroll
            for (int r = 0; r < 4; r++) {
                float sraw = (r < 2) ? (float)s01[r] : (float)s23[r - 2];
                float sn = (sraw - smin) * invr;
                float g = acc[mi][ni][r];
                float d2 = fmaxf(sqi[r] + sqj[ni] - 2.f * g, 0.f);
                float eud = (d2 > 0.f) ? sqrtf(d2) * invem : 0.f;
                float dist = eud + sn;
                bool pos = sn > 0.5f;
                float pv = pos ? __expf(dist) : 0.f;
                float nv = pos ? 0.f : __expf(1.0f - dist);
                ps[r] += pv;  ns[r] += nv;
                cpsum[ni] += pv;  cnsum[ni] += nv;
            }
        }
        #pragma unroll
        for (int r = 0; r < 4; r++) {
            #pragma unroll
            for (int m = 1; m < 16; m <<= 1) {
                ps[r] += __shfl_xor(ps[r], m);
                ns[r] += __shfl_xor(ns[r], m);
            }
            if (l15 == 0) {
                int rr = wm + mi * 16 + quad * 4 + r;
                rP[rr][wid & 1] = ps[r];
                rN[rr][wid & 1] = ns[r];
            }
        }
    }
    #pragma unroll
    for (int ni = 0; ni < 4; ni++) {
        #pragma unroll
        for (int m = 16; m < 64; m <<= 1) {
            cpsum[ni] += __shfl_xor(cpsum[ni], m);
            cnsum[ni] += __shfl_xor(cnsum[ni], m);
        }
        if (quad == 0) {
            int cc = wn + ni * 16 + l15;
            cP[cc][wid >> 1] = cpsum[ni];
            cN[cc][wid >> 1] = cnsum[ni];
        }
    }
    __syncthreads();
    if (tid < TILE) {
        atomicAdd(&pos_sums[bi * TILE + tid], rP[tid][0] + rP[tid][1]);
        atomicAdd(&neg_sums[bi * TILE + tid], rN[tid][0] + rN[tid][1]);
        if (bi != bj) {
            atomicAdd(&pos_sums[bj * TILE + tid], cP[tid][0] + cP[tid][1]);
            atomicAdd(&neg_sums[bj * TILE + tid], cN[tid][0] + cN[tid][1]);
        }
    }
}

// ------------------------------------------------------------- finalize ----
__global__ __launch_bounds__(256) void finalize_kernel(
    const float* __restrict__ pos_sums, const float* __restrict__ neg_sums,
    float* __restrict__ out) {
    int t = threadIdx.x;
    float acc = 0.f;
    for (int i = t; i < B_N; i += 256) {
        float p = pos_sums[i], n = neg_sums[i];
        float pl = fmaxf(logf(p), 0.f);
        float nl = (n > 0.f) ? fmaxf(logf(n), 0.f) : 0.f;
        acc += pl + nl;
    }
    #pragma unroll
    for (int m = 1; m < 64; m <<= 1) acc += __shfl_xor(acc, m);
    __shared__ float w4[4];
    if ((t & 63) == 0) w4[t >> 6] = acc;
    __syncthreads();
    if (t == 0) out[0] = (w4[0] + w4[1] + w4[2] + w4[3]) / (float)B_N;
}

// ------------------------------------------------------------------ entry ----
extern "C" void kernel_launch(void* const* d_in, const int* in_sizes, int n_in,
                              void* d_out, int out_size, void* d_ws, size_t ws_size,
                              hipStream_t stream) {
    const float* outputs = (const float*)d_in[0];
    const float* labels  = (const float*)d_in[1];
    float* out = (float*)d_out;
    char* ws = (char*)d_ws;
    __hip_bfloat16* Obp = (__hip_bfloat16*)(ws);
    __hip_bfloat16* Lnp = (__hip_bfloat16*)(ws + 4194304);
    float* sq           = (float*)(ws + 6291456);
    float* pos_sums     = (float*)(ws + 6324224);
    float* neg_sums     = (float*)(ws + 6356992);
    unsigned* stats     = (unsigned*)(ws + 6389760);
    unsigned* simT      = (unsigned*)(ws + 6389824);
    unsigned* eudT      = (unsigned*)(ws + 74547264);
    int big = (ws_size >= WS_NEEDED) ? 1 : 0;

    prep_kernel<<<B_N / 16, 256, 0, stream>>>(outputs, labels, Obp, Lnp, sq,
                                              pos_sums, neg_sums, stats);
    if (big) {
        stats_kernel<1><<<NTRI, 256, 0, stream>>>((const short*)Lnp,
                                                  (const short*)Obp,
                                                  sq, stats, simT, eudT);
        loss_stream_kernel<<<NTRI, 256, 0, stream>>>(simT, eudT, stats,
                                                     pos_sums, neg_sums);
    } else {
        stats_kernel<0><<<NTRI, 256, 0, stream>>>((const short*)Lnp,
                                                  (const short*)Obp,
                                                  sq, stats, simT, eudT);
        loss_recompute_kernel<<<NTRI, 256, 0, stream>>>((const short*)Lnp,
                                                        (const short*)Obp,
                                                        sq, stats,
                                                        pos_sums, neg_sums);
    }
    finalize_kernel<<<1, 256, 0, stream>>>(pos_sums, neg_sums, out);
}